// Round 3
// baseline (1740.875 us; speedup 1.0000x reference)
//
#include <hip/hip_runtime.h>

#define NN 100000
#define NE 3200000
#define NBIN 1563          // ceil(NN/64) bins of 64 dst nodes
#define CHUNK 8192
#define NBLK 391           // ceil(NE/CHUNK)
#define SRCMASK ((1u << 26) - 1)

__device__ __forceinline__ unsigned short f2bf(float f) {
    unsigned u = __float_as_uint(f);
    u += 0x7FFFu + ((u >> 16) & 1u);
    return (unsigned short)(u >> 16);
}
__device__ __forceinline__ float bf2f(unsigned short s) {
    return __uint_as_float(((unsigned)s) << 16);
}

// ---- pass 1: per-chunk histogram of dst bins ----
__global__ __launch_bounds__(256) void k_hist(const int* __restrict__ dst,
                                              int* __restrict__ hist2d) {
    __shared__ int hist[NBIN];
    int t = threadIdx.x;
    for (int j = t; j < NBIN; j += 256) hist[j] = 0;
    __syncthreads();
    int base = blockIdx.x * CHUNK;
#pragma unroll
    for (int i = 0; i < CHUNK / 256; i++) {
        int e = base + i * 256 + t;
        if (e < NE) atomicAdd(&hist[((unsigned)dst[e]) >> 6], 1);
    }
    __syncthreads();
    int* row = hist2d + (size_t)blockIdx.x * NBIN;
    for (int j = t; j < NBIN; j += 256) row[j] = hist[j];
}

// ---- pass 2a: per bin, exclusive scan across the 391 chunk counts ----
__global__ __launch_bounds__(256) void k_scanA(const int* __restrict__ hist2d,
                                               int* __restrict__ base2d_t,
                                               int* __restrict__ binTotal) {
    __shared__ int sd[256];
    int j = blockIdx.x;
    int t = threadIdx.x;
    int b0 = 2 * t, b1 = 2 * t + 1;
    int v0 = (b0 < NBLK) ? hist2d[(size_t)b0 * NBIN + j] : 0;
    int v1 = (b1 < NBLK) ? hist2d[(size_t)b1 * NBIN + j] : 0;
    int ps = v0 + v1;
    sd[t] = ps;
    __syncthreads();
    for (int o = 1; o < 256; o <<= 1) {
        int x = (t >= o) ? sd[t - o] : 0;
        __syncthreads();
        sd[t] += x;
        __syncthreads();
    }
    int excl = sd[t] - ps;
    if (b0 < NBLK) base2d_t[(size_t)j * NBLK + b0] = excl;
    if (b1 < NBLK) base2d_t[(size_t)j * NBLK + b1] = excl + v0;
    if (t == 255) binTotal[j] = sd[255];
}

// ---- pass 2b: exclusive scan of bin totals ----
#define SCB_PER 7
__global__ __launch_bounds__(256) void k_scanB(const int* __restrict__ binTotal,
                                               int* __restrict__ binBase) {
    __shared__ int sd[256];
    int t = threadIdx.x;
    int base = t * SCB_PER;
    int v[SCB_PER];
    int loc = 0;
#pragma unroll
    for (int i = 0; i < SCB_PER; i++) {
        int idx = base + i;
        int c = (idx < NBIN) ? binTotal[idx] : 0;
        v[i] = loc;
        loc += c;
    }
    sd[t] = loc;
    __syncthreads();
    for (int o = 1; o < 256; o <<= 1) {
        int x = (t >= o) ? sd[t - o] : 0;
        __syncthreads();
        sd[t] += x;
        __syncthreads();
    }
    int excl = sd[t] - loc;
#pragma unroll
    for (int i = 0; i < SCB_PER; i++) {
        int idx = base + i;
        if (idx < NBIN) binBase[idx] = excl + v[i];
    }
    if (t == 255) binBase[NBIN] = sd[255];
}

// ---- pass 3: counting-sort scatter into exact slots (no global atomics) ----
__global__ __launch_bounds__(256) void k_binscatter(const int* __restrict__ src,
                                                    const int* __restrict__ dst,
                                                    const float* __restrict__ ew,
                                                    const int* __restrict__ base2d_t,
                                                    const int* __restrict__ binBase,
                                                    uint2* __restrict__ bucket) {
    __shared__ int cur[NBIN];
    int t = threadIdx.x;
    int blk = blockIdx.x;
    for (int j = t; j < NBIN; j += 256)
        cur[j] = binBase[j] + base2d_t[(size_t)j * NBLK + blk];
    __syncthreads();
    int base = blk * CHUNK;
#pragma unroll
    for (int i = 0; i < CHUNK / 256; i++) {
        int e = base + i * 256 + t;
        if (e < NE) {
            unsigned d = (unsigned)dst[e];
            unsigned s = (unsigned)src[e];
            float w = ew[e];
            int j = d >> 6;
            int pos = atomicAdd(&cur[j], 1);
            bucket[pos] = make_uint2(s | ((d & 63u) << 26), __float_as_uint(w));
        }
    }
}

// ---- pass 4: per-bin weighted degree -> dinv ----
__global__ __launch_bounds__(256) void k_degB(const uint2* __restrict__ bucket,
                                              const int* __restrict__ binBase,
                                              float* __restrict__ dinv, int n) {
    __shared__ float deg[64];
    int t = threadIdx.x;
    int j = blockIdx.x;
    if (t < 64) deg[t] = 0.f;
    __syncthreads();
    int beg = binBase[j], end = binBase[j + 1];
    for (int i = beg + t; i < end; i += 256) {
        uint2 v = bucket[i];
        atomicAdd(&deg[v.x >> 26], __uint_as_float(v.y));
    }
    __syncthreads();
    if (t < 64) {
        int g = j * 64 + t;
        if (g < n) dinv[g] = rsqrtf(1.0f + deg[t]);
    }
}

// ---- GEMM: h16[N,64] = bf16(x[N,256] @ W[256,64]) ----
#define GR 128
#define GKC 64
#define XS_STRIDE 68
__global__ __launch_bounds__(256) void k_gemm(const float* __restrict__ x,
                                              const float* __restrict__ W,
                                              unsigned short* __restrict__ h16, int n) {
    __shared__ float xs[GR][XS_STRIDE];
    __shared__ float wsh[GKC][64];
    int t = threadIdx.x;
    int tx = t & 15;
    int ty = t >> 4;
    int rbase = blockIdx.x * GR;
    float acc[8][4];
#pragma unroll
    for (int i = 0; i < 8; i++)
#pragma unroll
        for (int jj = 0; jj < 4; jj++) acc[i][jj] = 0.0f;

    for (int k0 = 0; k0 < 256; k0 += GKC) {
        const float4* wsrc = (const float4*)(W + k0 * 64);
        float4* wdst = (float4*)(&wsh[0][0]);
#pragma unroll
        for (int p = 0; p < 4; p++) wdst[p * 256 + t] = wsrc[p * 256 + t];
#pragma unroll
        for (int p = 0; p < 8; p++) {
            int f4 = p * 256 + t;
            int r = f4 >> 4;
            int kq = (f4 & 15) << 2;
            int row = rbase + r;
            float4 val = make_float4(0.f, 0.f, 0.f, 0.f);
            if (row < n) val = *(const float4*)(x + (size_t)row * 256 + k0 + kq);
            *(float4*)(&xs[r][kq]) = val;
        }
        __syncthreads();
        int r0 = ty * 8, c0 = tx * 4;
#pragma unroll
        for (int kk = 0; kk < GKC; kk += 4) {
            float4 wv[4];
#pragma unroll
            for (int m = 0; m < 4; m++) wv[m] = *(const float4*)(&wsh[kk + m][c0]);
#pragma unroll
            for (int i = 0; i < 8; i++) {
                float4 xv = *(const float4*)(&xs[r0 + i][kk]);
                acc[i][0] += xv.x * wv[0].x + xv.y * wv[1].x + xv.z * wv[2].x + xv.w * wv[3].x;
                acc[i][1] += xv.x * wv[0].y + xv.y * wv[1].y + xv.z * wv[2].y + xv.w * wv[3].y;
                acc[i][2] += xv.x * wv[0].z + xv.y * wv[1].z + xv.z * wv[2].z + xv.w * wv[3].z;
                acc[i][3] += xv.x * wv[0].w + xv.y * wv[1].w + xv.z * wv[2].w + xv.w * wv[3].w;
            }
        }
        __syncthreads();
    }
    int r0 = ty * 8, c0 = tx * 4;
#pragma unroll
    for (int i = 0; i < 8; i++) {
        int row = rbase + r0 + i;
        if (row < n) {
            uint2 pv;
            pv.x = (unsigned)f2bf(acc[i][0]) | ((unsigned)f2bf(acc[i][1]) << 16);
            pv.y = (unsigned)f2bf(acc[i][2]) | ((unsigned)f2bf(acc[i][3]) << 16);
            *(uint2*)(h16 + (size_t)row * 64 + c0) = pv;
        }
    }
}

// ---- pass 5: per-bin aggregate + self-loop + bias + leaky-relu + LN ----
__global__ __launch_bounds__(256) void k_aggC(const unsigned short* __restrict__ h16,
                                              const float* __restrict__ dinv,
                                              const uint2* __restrict__ bucket,
                                              const int* __restrict__ binBase,
                                              const float* __restrict__ bias,
                                              const float* __restrict__ gamma,
                                              const float* __restrict__ beta,
                                              float* __restrict__ out, int n) {
    __shared__ float acc[64 * 64];
    __shared__ float ldi[64];
    int t = threadIdx.x, lane = t & 63, wid = t >> 6;
    int j = blockIdx.x, nb0 = j * 64;
    for (int i = t; i < 64 * 64; i += 256) acc[i] = 0.f;
    if (t < 64) {
        int g = nb0 + t;
        ldi[t] = (g < n) ? dinv[g] : 0.f;
    }
    __syncthreads();
    int beg = binBase[j], end = binBase[j + 1];
    for (int j0 = beg + wid * 64; j0 < end; j0 += 256) {
        int myj = j0 + lane;
        unsigned pk = 0;
        float wsrc = 0.f;
        if (myj < end) {
            uint2 v = bucket[myj];
            pk = v.x;
            wsrc = __uint_as_float(v.y) * dinv[pk & SRCMASK];
        }
        int c = end - j0;
        if (c > 64) c = 64;
        for (int i2 = 0; i2 < c; i2++) {
            unsigned p = __shfl(pk, i2, 64);
            float wi = __shfl(wsrc, i2, 64);
            int sl = p & SRCMASK;
            int dl = p >> 26;
            wi *= ldi[dl];
            float hv = bf2f(h16[(size_t)sl * 64 + lane]);
            atomicAdd(&acc[dl * 64 + lane], hv * wi);
        }
    }
    __syncthreads();
    float bv = bias[lane], gv = gamma[lane], btv = beta[lane];
    for (int k = 0; k < 16; k++) {
        int nl = wid * 16 + k;
        int g = nb0 + nl;
        if (g >= n) break;
        float di = ldi[nl];
        float hv = bf2f(h16[(size_t)g * 64 + lane]);
        float y = acc[nl * 64 + lane] + hv * di * di + bv;
        y = (y >= 0.f) ? y : 0.01f * y;
        float sum = y;
#pragma unroll
        for (int o = 32; o > 0; o >>= 1) sum += __shfl_xor(sum, o, 64);
        float mu = sum * (1.f / 64.f);
        float d = y - mu;
        float vv = d * d;
#pragma unroll
        for (int o = 32; o > 0; o >>= 1) vv += __shfl_xor(vv, o, 64);
        vv *= (1.f / 64.f);
        out[(size_t)g * 64 + lane] = d * rsqrtf(vv + 1e-5f) * gv + btv;
    }
}

extern "C" void kernel_launch(void* const* d_in, const int* in_sizes, int n_in,
                              void* d_out, int out_size, void* d_ws, size_t ws_size,
                              hipStream_t stream) {
    const float* x = (const float*)d_in[0];
    const int* ei = (const int*)d_in[1];
    const float* ew = (const float*)d_in[2];
    const float* W = (const float*)d_in[3];
    const float* b = (const float*)d_in[4];
    const float* gamma = (const float*)d_in[5];
    const float* beta = (const float*)d_in[6];
    float* out = (float*)d_out;

    const int n = NN, e = NE;
    const int* src = ei;
    const int* dst = ei + e;

    char* ws = (char*)d_ws;
    size_t o = 0;
    auto alloc = [&](size_t bytes) -> char* {
        char* r = ws + o;
        o = (o + bytes + 255) & ~(size_t)255;
        return r;
    };

    int* hist2d = (int*)alloc((size_t)NBLK * NBIN * 4);
    int* base2d_t = (int*)alloc((size_t)NBIN * NBLK * 4);
    int* binTotal = (int*)alloc((size_t)NBIN * 4);
    int* binBase = (int*)alloc((size_t)(NBIN + 1) * 4);
    uint2* bucket = (uint2*)alloc((size_t)e * 8);
    float* dinv = (float*)alloc((size_t)n * 4);
    unsigned short* h16 = (unsigned short*)alloc((size_t)n * 64 * 2);
    (void)ws_size;

    int nb_gemm = (n + GR - 1) / GR;

    k_hist<<<NBLK, 256, 0, stream>>>(dst, hist2d);
    k_scanA<<<NBIN, 256, 0, stream>>>(hist2d, base2d_t, binTotal);
    k_scanB<<<1, 256, 0, stream>>>(binTotal, binBase);
    k_binscatter<<<NBLK, 256, 0, stream>>>(src, dst, ew, base2d_t, binBase, bucket);
    k_degB<<<NBIN, 256, 0, stream>>>(bucket, binBase, dinv, n);
    k_gemm<<<nb_gemm, 256, 0, stream>>>(x, W, h16, n);
    k_aggC<<<NBIN, 256, 0, stream>>>(h16, dinv, bucket, binBase, b, gamma, beta, out, n);
}

// Round 4
// 1612.529 us; speedup vs baseline: 1.0796x; 1.0796x over previous
//
#include <hip/hip_runtime.h>

#define NN 100000
#define NE 3200000
#define NBIN 3125          // NN/32 bins of 32 dst nodes (exact)
#define BINSH 5
#define CHUNK 8192
#define NBLK 391           // ceil(NE/CHUNK)
#define SRCMASK ((1u << 26) - 1)

__device__ __forceinline__ unsigned short f2bf(float f) {
    unsigned u = __float_as_uint(f);
    u += 0x7FFFu + ((u >> 16) & 1u);
    return (unsigned short)(u >> 16);
}
__device__ __forceinline__ float bf2f(unsigned short s) {
    return __uint_as_float(((unsigned)s) << 16);
}

// ---- pass 1: per-chunk histogram of dst bins ----
__global__ __launch_bounds__(256) void k_hist(const int* __restrict__ dst,
                                              int* __restrict__ hist2d) {
    __shared__ int hist[NBIN];
    int t = threadIdx.x;
    for (int j = t; j < NBIN; j += 256) hist[j] = 0;
    __syncthreads();
    int base = blockIdx.x * CHUNK;
#pragma unroll
    for (int i = 0; i < CHUNK / 256; i++) {
        int e = base + i * 256 + t;
        if (e < NE) atomicAdd(&hist[((unsigned)dst[e]) >> BINSH], 1);
    }
    __syncthreads();
    int* row = hist2d + (size_t)blockIdx.x * NBIN;
    for (int j = t; j < NBIN; j += 256) row[j] = hist[j];
}

// ---- pass 2a: per bin, exclusive scan across the NBLK chunk counts ----
__global__ __launch_bounds__(256) void k_scanA(const int* __restrict__ hist2d,
                                               int* __restrict__ base2d_t,
                                               int* __restrict__ binTotal) {
    __shared__ int sd[256];
    int j = blockIdx.x;
    int t = threadIdx.x;
    int b0 = 2 * t, b1 = 2 * t + 1;
    int v0 = (b0 < NBLK) ? hist2d[(size_t)b0 * NBIN + j] : 0;
    int v1 = (b1 < NBLK) ? hist2d[(size_t)b1 * NBIN + j] : 0;
    int ps = v0 + v1;
    sd[t] = ps;
    __syncthreads();
    for (int o = 1; o < 256; o <<= 1) {
        int x = (t >= o) ? sd[t - o] : 0;
        __syncthreads();
        sd[t] += x;
        __syncthreads();
    }
    int excl = sd[t] - ps;
    if (b0 < NBLK) base2d_t[(size_t)j * NBLK + b0] = excl;
    if (b1 < NBLK) base2d_t[(size_t)j * NBLK + b1] = excl + v0;
    if (t == 255) binTotal[j] = sd[255];
}

// ---- pass 2b: exclusive scan of bin totals ----
#define SCB_PER 13
__global__ __launch_bounds__(256) void k_scanB(const int* __restrict__ binTotal,
                                               int* __restrict__ binBase) {
    __shared__ int sd[256];
    int t = threadIdx.x;
    int base = t * SCB_PER;
    int v[SCB_PER];
    int loc = 0;
#pragma unroll
    for (int i = 0; i < SCB_PER; i++) {
        int idx = base + i;
        int c = (idx < NBIN) ? binTotal[idx] : 0;
        v[i] = loc;
        loc += c;
    }
    sd[t] = loc;
    __syncthreads();
    for (int o = 1; o < 256; o <<= 1) {
        int x = (t >= o) ? sd[t - o] : 0;
        __syncthreads();
        sd[t] += x;
        __syncthreads();
    }
    int excl = sd[t] - loc;
#pragma unroll
    for (int i = 0; i < SCB_PER; i++) {
        int idx = base + i;
        if (idx < NBIN) binBase[idx] = excl + v[i];
    }
    if (t == 255) binBase[NBIN] = sd[255];
}

// ---- pass 3: counting-sort scatter into exact slots (no global atomics) ----
__global__ __launch_bounds__(256) void k_binscatter(const int* __restrict__ src,
                                                    const int* __restrict__ dst,
                                                    const float* __restrict__ ew,
                                                    const int* __restrict__ base2d_t,
                                                    const int* __restrict__ binBase,
                                                    uint2* __restrict__ bucket) {
    __shared__ int cur[NBIN];
    int t = threadIdx.x;
    int blk = blockIdx.x;
    for (int j = t; j < NBIN; j += 256)
        cur[j] = binBase[j] + base2d_t[(size_t)j * NBLK + blk];
    __syncthreads();
    int base = blk * CHUNK;
#pragma unroll
    for (int i = 0; i < CHUNK / 256; i++) {
        int e = base + i * 256 + t;
        if (e < NE) {
            unsigned d = (unsigned)dst[e];
            unsigned s = (unsigned)src[e];
            float w = ew[e];
            int j = d >> BINSH;
            int pos = atomicAdd(&cur[j], 1);
            bucket[pos] = make_uint2(s | ((d & 31u) << 26), __float_as_uint(w));
        }
    }
}

// ---- pass 4: per-bin weighted degree -> dinv ----
__global__ __launch_bounds__(256) void k_degB(const uint2* __restrict__ bucket,
                                              const int* __restrict__ binBase,
                                              float* __restrict__ dinv, int n) {
    __shared__ float deg[32];
    int t = threadIdx.x;
    int j = blockIdx.x;
    if (t < 32) deg[t] = 0.f;
    __syncthreads();
    int beg = binBase[j], end = binBase[j + 1];
    for (int i = beg + t; i < end; i += 256) {
        uint2 v = bucket[i];
        atomicAdd(&deg[v.x >> 26], __uint_as_float(v.y));
    }
    __syncthreads();
    if (t < 32) {
        int g = j * 32 + t;
        if (g < n) dinv[g] = rsqrtf(1.0f + deg[t]);
    }
}

// ---- GEMM: h16[N,64] = bf16(x[N,256] @ W[256,64]) ----
#define GR 128
#define GKC 64
#define XS_STRIDE 68
__global__ __launch_bounds__(256) void k_gemm(const float* __restrict__ x,
                                              const float* __restrict__ W,
                                              unsigned short* __restrict__ h16, int n) {
    __shared__ float xs[GR][XS_STRIDE];
    __shared__ float wsh[GKC][64];
    int t = threadIdx.x;
    int tx = t & 15;
    int ty = t >> 4;
    int rbase = blockIdx.x * GR;
    float acc[8][4];
#pragma unroll
    for (int i = 0; i < 8; i++)
#pragma unroll
        for (int jj = 0; jj < 4; jj++) acc[i][jj] = 0.0f;

    for (int k0 = 0; k0 < 256; k0 += GKC) {
        const float4* wsrc = (const float4*)(W + k0 * 64);
        float4* wdst = (float4*)(&wsh[0][0]);
#pragma unroll
        for (int p = 0; p < 4; p++) wdst[p * 256 + t] = wsrc[p * 256 + t];
#pragma unroll
        for (int p = 0; p < 8; p++) {
            int f4 = p * 256 + t;
            int r = f4 >> 4;
            int kq = (f4 & 15) << 2;
            int row = rbase + r;
            float4 val = make_float4(0.f, 0.f, 0.f, 0.f);
            if (row < n) val = *(const float4*)(x + (size_t)row * 256 + k0 + kq);
            *(float4*)(&xs[r][kq]) = val;
        }
        __syncthreads();
        int r0 = ty * 8, c0 = tx * 4;
#pragma unroll
        for (int kk = 0; kk < GKC; kk += 4) {
            float4 wv[4];
#pragma unroll
            for (int m = 0; m < 4; m++) wv[m] = *(const float4*)(&wsh[kk + m][c0]);
#pragma unroll
            for (int i = 0; i < 8; i++) {
                float4 xv = *(const float4*)(&xs[r0 + i][kk]);
                acc[i][0] += xv.x * wv[0].x + xv.y * wv[1].x + xv.z * wv[2].x + xv.w * wv[3].x;
                acc[i][1] += xv.x * wv[0].y + xv.y * wv[1].y + xv.z * wv[2].y + xv.w * wv[3].y;
                acc[i][2] += xv.x * wv[0].z + xv.y * wv[1].z + xv.z * wv[2].z + xv.w * wv[3].z;
                acc[i][3] += xv.x * wv[0].w + xv.y * wv[1].w + xv.z * wv[2].w + xv.w * wv[3].w;
            }
        }
        __syncthreads();
    }
    int r0 = ty * 8, c0 = tx * 4;
#pragma unroll
    for (int i = 0; i < 8; i++) {
        int row = rbase + r0 + i;
        if (row < n) {
            uint2 pv;
            pv.x = (unsigned)f2bf(acc[i][0]) | ((unsigned)f2bf(acc[i][1]) << 16);
            pv.y = (unsigned)f2bf(acc[i][2]) | ((unsigned)f2bf(acc[i][3]) << 16);
            *(uint2*)(h16 + (size_t)row * 64 + c0) = pv;
        }
    }
}

// ---- pass 5: per-bin aggregate (4 edges/wave-step) + epilogue ----
#define ACCS 68   // padded row stride: different dl -> different bank sets
__global__ __launch_bounds__(256) void k_aggC(const unsigned short* __restrict__ h16,
                                              const float* __restrict__ dinv,
                                              const uint2* __restrict__ bucket,
                                              const int* __restrict__ binBase,
                                              const float* __restrict__ bias,
                                              const float* __restrict__ gamma,
                                              const float* __restrict__ beta,
                                              float* __restrict__ out, int n) {
    __shared__ float acc[32 * ACCS];
    __shared__ float ldi[32];
    int t = threadIdx.x, lane = t & 63, wid = t >> 6;
    int grp = lane >> 4, sub = lane & 15;
    int j = blockIdx.x, nb0 = j * 32;
    for (int i = t; i < 32 * ACCS; i += 256) acc[i] = 0.f;
    if (t < 32) ldi[t] = dinv[nb0 + t];
    __syncthreads();
    int beg = binBase[j], end = binBase[j + 1];
    for (int j0 = beg + wid * 64; j0 < end; j0 += 256) {
        int myj = j0 + lane;
        int pk = 0;
        float wn = 0.f;
        if (myj < end) {
            uint2 v = bucket[myj];
            pk = (int)v.x;
            unsigned u = v.x;
            wn = __uint_as_float(v.y) * dinv[u & SRCMASK] * ldi[u >> 26];
        }
#pragma unroll 4
        for (int s = 0; s < 16; s++) {
            int idx = 4 * s + grp;
            unsigned p = (unsigned)__shfl(pk, idx, 64);
            float wi = __shfl(wn, idx, 64);
            int sl = p & SRCMASK;
            int dl = p >> 26;
            uint2 hv = *(const uint2*)(h16 + (size_t)sl * 64 + sub * 4);
            float f0 = bf2f((unsigned short)(hv.x & 0xffffu));
            float f1 = bf2f((unsigned short)(hv.x >> 16));
            float f2 = bf2f((unsigned short)(hv.y & 0xffffu));
            float f3 = bf2f((unsigned short)(hv.y >> 16));
            float* a = &acc[dl * ACCS + sub * 4];
            atomicAdd(a + 0, f0 * wi);
            atomicAdd(a + 1, f1 * wi);
            atomicAdd(a + 2, f2 * wi);
            atomicAdd(a + 3, f3 * wi);
        }
    }
    __syncthreads();
    float bv = bias[lane], gv = gamma[lane], btv = beta[lane];
#pragma unroll
    for (int k = 0; k < 8; k++) {
        int nl = wid * 8 + k;
        int g = nb0 + nl;
        float di = ldi[nl];
        float hvf = bf2f(h16[(size_t)g * 64 + lane]);
        float y = acc[nl * ACCS + lane] + hvf * di * di + bv;
        y = (y >= 0.f) ? y : 0.01f * y;
        float sum = y;
#pragma unroll
        for (int o = 32; o > 0; o >>= 1) sum += __shfl_xor(sum, o, 64);
        float mu = sum * (1.f / 64.f);
        float d = y - mu;
        float vv = d * d;
#pragma unroll
        for (int o = 32; o > 0; o >>= 1) vv += __shfl_xor(vv, o, 64);
        vv *= (1.f / 64.f);
        out[(size_t)g * 64 + lane] = d * rsqrtf(vv + 1e-5f) * gv + btv;
    }
}

extern "C" void kernel_launch(void* const* d_in, const int* in_sizes, int n_in,
                              void* d_out, int out_size, void* d_ws, size_t ws_size,
                              hipStream_t stream) {
    const float* x = (const float*)d_in[0];
    const int* ei = (const int*)d_in[1];
    const float* ew = (const float*)d_in[2];
    const float* W = (const float*)d_in[3];
    const float* b = (const float*)d_in[4];
    const float* gamma = (const float*)d_in[5];
    const float* beta = (const float*)d_in[6];
    float* out = (float*)d_out;

    const int n = NN, e = NE;
    const int* src = ei;
    const int* dst = ei + e;

    char* ws = (char*)d_ws;
    size_t o = 0;
    auto alloc = [&](size_t bytes) -> char* {
        char* r = ws + o;
        o = (o + bytes + 255) & ~(size_t)255;
        return r;
    };

    int* hist2d = (int*)alloc((size_t)NBLK * NBIN * 4);
    int* base2d_t = (int*)alloc((size_t)NBIN * NBLK * 4);
    int* binTotal = (int*)alloc((size_t)NBIN * 4);
    int* binBase = (int*)alloc((size_t)(NBIN + 1) * 4);
    uint2* bucket = (uint2*)alloc((size_t)e * 8);
    float* dinv = (float*)alloc((size_t)n * 4);
    unsigned short* h16 = (unsigned short*)alloc((size_t)n * 64 * 2);
    (void)ws_size;

    int nb_gemm = (n + GR - 1) / GR;

    k_hist<<<NBLK, 256, 0, stream>>>(dst, hist2d);
    k_scanA<<<NBIN, 256, 0, stream>>>(hist2d, base2d_t, binTotal);
    k_scanB<<<1, 256, 0, stream>>>(binTotal, binBase);
    k_binscatter<<<NBLK, 256, 0, stream>>>(src, dst, ew, base2d_t, binBase, bucket);
    k_degB<<<NBIN, 256, 0, stream>>>(bucket, binBase, dinv, n);
    k_gemm<<<nb_gemm, 256, 0, stream>>>(x, W, h16, n);
    k_aggC<<<NBIN, 256, 0, stream>>>(h16, dinv, bucket, binBase, b, gamma, beta, out, n);
}